// Round 1
// baseline (168.067 us; speedup 1.0000x reference)
//
#include <hip/hip_runtime.h>
#include <hip/hip_bf16.h>

// ContrastiveLoss: loss = mean_i [ logsumexp_j(logits[i,:]) - pos_sim[i,i] ]
// logits = [20*xn@tn^T | 20*xn@hn^T + I], rows normalized.
// Round 9: keep R8's i8 MFMA + XOR-swizzled 16B-chunk staging (0 conflicts
// measured), but replace the serial {sync, stage, sync(vmcnt0-drain), compute}
// K-loop with the catalog-T3 "minimum 2-phase" double-buffered pipeline:
//   stage(buf^1, kb+1)  ->  ds_read+MFMA(buf, kb)  ->  asm vmcnt(0)  ->
//   raw s_barrier
// so the global_load_lds transfer+latency (~1400 cyc/iter) hides under the
// MFMA cluster (~1300 cyc/iter/SIMD) instead of serializing with it.
// Raw s_barrier + inline-asm waitcnt prevent the compiler's forced
// vmcnt(0)+lgkmcnt(0) drain that __syncthreads emits (the R8 stall:
// MfmaUtil 18%, ~5480 cyc/K-iter vs ~1300 of MFMA work).
//  - LDS 2x(16+16) KiB = 64 KiB -> still 2 blocks/CU (matches measured
//    residency; occupancy unchanged).
//  - scaled-MFMA banned (R2/R4: C/D stays in VGPRs, 252+ regs, 10% occ).
//  - b64 LDS reads banned (R5: ~28 conflict-cyc each); everything b128.
//  - logit = acc * (20/127^2); diag cancellation makes i8 loss error ~1e-3.

#define AS1 __attribute__((address_space(1)))
#define AS3 __attribute__((address_space(3)))

constexpr int N = 4096;
constexpr int D = 1024;            // elements per row == bytes per i8 row
constexpr float QSCALE = 127.0f;
constexpr float LSCALE = 20.0f / (127.0f * 127.0f);  // acc -> logit
constexpr float CBIAS = 21.0f;     // >= max possible logit (20*1 + 1)

typedef int i32x4 __attribute__((ext_vector_type(4)));

// 3072 blocks x 256. One row per wave; lane holds 16 CONTIGUOUS floats ->
// 16 int8 bytes -> one uint4 store at byte 16*lane (wave writes 1KB contig).
// Blocks 0..15 also zero rowsum so gemm's atomics start clean.
__global__ __launch_bounds__(256) void normalize_kernel(
    const float* __restrict__ in0, const float* __restrict__ in1,
    const float* __restrict__ in2, unsigned char* __restrict__ Abuf,
    unsigned char* __restrict__ Bbuf, float* __restrict__ rowsum) {
    const int t = threadIdx.x, lane = t & 63, wave = t >> 6;
    if (blockIdx.x < 16) rowsum[blockIdx.x * 256 + t] = 0.f;
    const int row = blockIdx.x * 4 + wave;  // 0..12287
    const int mat = row >> 12, r = row & (N - 1);
    const float* src = (mat == 0) ? in0 : (mat == 1) ? in1 : in2;
    unsigned char* dst = (mat == 0) ? (Abuf + (size_t)r * D)
                       : (mat == 1) ? (Bbuf + (size_t)r * D)
                                    : (Bbuf + (size_t)(r + N) * D);
    const float4* s4 = (const float4*)(src + (size_t)r * D);
    float4 v[4];
    float p = 0.f;
#pragma unroll
    for (int j = 0; j < 4; ++j) {
        v[j] = s4[4 * lane + j];  // floats 16*lane .. 16*lane+15
        p += v[j].x * v[j].x + v[j].y * v[j].y + v[j].z * v[j].z + v[j].w * v[j].w;
    }
#pragma unroll
    for (int m = 1; m < 64; m <<= 1) p += __shfl_xor(p, m);
    const float s = QSCALE / fmaxf(sqrtf(p), 1e-8f);
    uint4 o;
    unsigned int w[4];
#pragma unroll
    for (int j = 0; j < 4; ++j) {
        int q0 = min(127, max(-127, __float2int_rn(v[j].x * s)));
        int q1 = min(127, max(-127, __float2int_rn(v[j].y * s)));
        int q2 = min(127, max(-127, __float2int_rn(v[j].z * s)));
        int q3 = min(127, max(-127, __float2int_rn(v[j].w * s)));
        w[j] = (q0 & 255) | ((q1 & 255) << 8) | ((q2 & 255) << 16)
             | ((unsigned)(q3 & 255) << 24);
    }
    o.x = w[0]; o.y = w[1]; o.z = w[2]; o.w = w[3];
    ((uint4*)dst)[lane] = o;
}

// 128x128 tile, BK=128 i8-bytes, 4 waves 2x2, wave 64x64 via 4x4 of
// 16x16x64 i8 MFMA, 2 K-substeps (h) per staged tile, b128 frag reads.
// A:[N,D] i8, B:[2N,D] i8, row-major (no permute: frag = 16 contig bytes,
// row = lane&15, k = (lane>>4)*16 + j).
// C/D: col = lane&15, row = (lane>>4)*4 + reg (m89-verified, shape-determined).
__global__ __launch_bounds__(256) void gemm_lse_kernel(
    const unsigned char* __restrict__ A, const unsigned char* __restrict__ B,
    float* __restrict__ rowsum, float* __restrict__ posdiag) {
    __shared__ __align__(16) char As[2][128 * 128];  // 2 x 16 KiB
    __shared__ __align__(16) char Bs[2][128 * 128];  // 2 x 16 KiB

    const int tid = threadIdx.x;
    const int lane = tid & 63;
    const int wave = tid >> 6;
    const int wr = wave >> 1, wc = wave & 1;
    const int quad = lane >> 4, colid = lane & 15;
    const int rowBase = blockIdx.y * 128;
    const int colBase = blockIdx.x * 128;

    i32x4 acc[4][4];
#pragma unroll
    for (int i = 0; i < 4; ++i)
#pragma unroll
        for (int j = 0; j < 4; ++j) acc[i][j] = {0, 0, 0, 0};

    // Staging (identical to R7/R8, measured 0 conflicts): 1024 16B
    // phys-chunks per 128x128B tile; thread t fills chunks t+256j. phys
    // chunk c -> row c>>3, phys col c&7; global logical col = (c&7)^(row&7).
    const int srow = tid >> 3;                      // 0..31
    const int scol = (tid & 7) ^ ((tid >> 3) & 7);  // 16B units
    const unsigned char* gA[4];
    const unsigned char* gB[4];
#pragma unroll
    for (int j = 0; j < 4; ++j) {
        gA[j] = A + (size_t)(rowBase + srow + 32 * j) * D + scol * 16;
        gB[j] = B + (size_t)(colBase + srow + 32 * j) * D + scol * 16;
    }

    // Frag offsets: K-half h (64 K-elems), row R: logical chunk h*4+quad,
    // phys = logical ^ (R&7). One b128 IS the i8 MFMA operand (i32x4).
    int aoff[4][2], boff[4][2];
#pragma unroll
    for (int rt = 0; rt < 4; ++rt) {
        const int R = wr * 64 + rt * 16 + colid;
#pragma unroll
        for (int h = 0; h < 2; ++h)
            aoff[rt][h] = R * 128 + ((h * 4 + quad) ^ (R & 7)) * 16;
    }
#pragma unroll
    for (int ct = 0; ct < 4; ++ct) {
        const int C = wc * 64 + ct * 16 + colid;
#pragma unroll
        for (int h = 0; h < 2; ++h)
            boff[ct][h] = C * 128 + ((h * 4 + quad) ^ (C & 7)) * 16;
    }

    // Prologue: stage K-tile 0 into buffer 0, drain, sync.
#pragma unroll
    for (int j = 0; j < 4; ++j) {
        __builtin_amdgcn_global_load_lds((const AS1 void*)(gA[j]),
            (AS3 void*)(As[0] + (tid + 256 * j) * 16), 16, 0, 0);
        __builtin_amdgcn_global_load_lds((const AS1 void*)(gB[j]),
            (AS3 void*)(Bs[0] + (tid + 256 * j) * 16), 16, 0, 0);
    }
    asm volatile("s_waitcnt vmcnt(0)" ::: "memory");
    __builtin_amdgcn_s_barrier();

    // 2-phase pipeline: stage(next) || compute(cur); vmcnt(0)+barrier at
    // iteration end (loads had the whole MFMA cluster to land). Buffer
    // being staged in iter kb was last READ in iter kb-1, whose end-barrier
    // already fenced all waves' ds_reads (consumed by MFMAs pre-barrier).
#pragma unroll
    for (int kb = 0; kb < 8; ++kb) {
        if (kb < 7) {
            const int k0 = (kb + 1) * 128;
            char* Ad = As[(kb + 1) & 1];
            char* Bd = Bs[(kb + 1) & 1];
#pragma unroll
            for (int j = 0; j < 4; ++j) {
                __builtin_amdgcn_global_load_lds((const AS1 void*)(gA[j] + k0),
                    (AS3 void*)(Ad + (tid + 256 * j) * 16), 16, 0, 0);
                __builtin_amdgcn_global_load_lds((const AS1 void*)(gB[j] + k0),
                    (AS3 void*)(Bd + (tid + 256 * j) * 16), 16, 0, 0);
            }
        }
        const char* Ab = As[kb & 1];
        const char* Bb = Bs[kb & 1];
#pragma unroll
        for (int h = 0; h < 2; ++h) {
            i32x4 a[4], b[4];
#pragma unroll
            for (int rt = 0; rt < 4; ++rt)
                a[rt] = *(const i32x4*)(Ab + aoff[rt][h]);
#pragma unroll
            for (int ct = 0; ct < 4; ++ct)
                b[ct] = *(const i32x4*)(Bb + boff[ct][h]);
            __builtin_amdgcn_s_setprio(1);
#pragma unroll
            for (int rt = 0; rt < 4; ++rt)
#pragma unroll
                for (int ct = 0; ct < 4; ++ct)
                    acc[rt][ct] = __builtin_amdgcn_mfma_i32_16x16x64_i8(
                        a[rt], b[ct], acc[rt][ct], 0, 0, 0);
            __builtin_amdgcn_s_setprio(0);
        }
        if (kb < 7) {
            asm volatile("s_waitcnt vmcnt(0)" ::: "memory");
            __builtin_amdgcn_s_barrier();
        }
    }

    // Epilogue: C map col = lane&15, row = quad*4 + reg.
#pragma unroll
    for (int rt = 0; rt < 4; ++rt) {
        float rsum[4] = {0.f, 0.f, 0.f, 0.f};
#pragma unroll
        for (int ct = 0; ct < 4; ++ct) {
#pragma unroll
            for (int reg = 0; reg < 4; ++reg) {
                const int grow = rowBase + wr * 64 + rt * 16 + quad * 4 + reg;
                const int gcol = colBase + wc * 64 + ct * 16 + colid;
                float logit = (float)acc[rt][ct][reg] * LSCALE;
                if (gcol == grow + N) logit += 1.0f;      // hard-negative weight
                if (gcol == grow) posdiag[grow] = logit;  // unique writer
                rsum[reg] += __expf(logit - CBIAS);
            }
        }
#pragma unroll
        for (int reg = 0; reg < 4; ++reg) {
            float v = rsum[reg];
            v += __shfl_xor(v, 1);
            v += __shfl_xor(v, 2);
            v += __shfl_xor(v, 4);
            v += __shfl_xor(v, 8);
            if (colid == 0) {
                const int grow = rowBase + wr * 64 + rt * 16 + quad * 4 + reg;
                atomicAdd(&rowsum[grow], v);
            }
        }
    }
}

__global__ __launch_bounds__(256) void finalize_kernel(
    const float* __restrict__ rowsum, const float* __restrict__ posdiag,
    float* __restrict__ out) {
    const int t = threadIdx.x;
    float s = 0.f;
    for (int i = t; i < N; i += 256)
        s += CBIAS + logf(rowsum[i]) - posdiag[i];
    for (int m = 32; m; m >>= 1) s += __shfl_down(s, m);
    __shared__ float red[4];
    const int lane = t & 63, wave = t >> 6;
    if (lane == 0) red[wave] = s;
    __syncthreads();
    if (t == 0) out[0] = (red[0] + red[1] + red[2] + red[3]) / (float)N;
}

extern "C" void kernel_launch(void* const* d_in, const int* in_sizes, int n_in,
                              void* d_out, int out_size, void* d_ws, size_t ws_size,
                              hipStream_t stream) {
    const float* in0 = (const float*)d_in[0];  // input   [N, D] fp32
    const float* in1 = (const float*)d_in[1];  // target  [N, D] fp32
    const float* in2 = (const float*)d_in[2];  // hardneg [N, D] fp32

    // Workspace: Abuf N*D i8 (4 MiB) | Bbuf 2N*D i8 (8 MiB) | rowsum | posdiag
    unsigned char* Abuf = (unsigned char*)d_ws;
    unsigned char* Bbuf = Abuf + (size_t)N * D;
    float* rowsum = (float*)(Bbuf + (size_t)2 * N * D);
    float* posdiag = rowsum + N;

    normalize_kernel<<<3 * N / 4, 256, 0, stream>>>(in0, in1, in2, Abuf, Bbuf,
                                                    rowsum);
    gemm_lse_kernel<<<dim3(2 * N / 128, N / 128), 256, 0, stream>>>(
        Abuf, Bbuf, rowsum, posdiag);
    finalize_kernel<<<1, 256, 0, stream>>>(rowsum, posdiag, (float*)d_out);
}

// Round 2
// 162.626 us; speedup vs baseline: 1.0335x; 1.0335x over previous
//
#include <hip/hip_runtime.h>
#include <hip/hip_bf16.h>

// ContrastiveLoss: loss = mean_i [ logsumexp_j(logits[i,:]) - pos_sim[i,i] ]
// logits = [20*xn@tn^T | 20*xn@hn^T + I], rows normalized.
// Round 10: T3+T4 deep pipeline (counted vmcnt, never 0 in main loop).
//  - R9 post-mortem: 2-slot dbuf with per-iter vmcnt(0) drain was NEUTRAL
//    (clean pass 72.6us == R8): the drain just moved, and 64KB LDS halved
//    residency. Catalog says the lever is counted-vmcnt depth, not dbuf.
//  - New: BM=256 x BN=128, BK=128B, 512 thr (8 waves 4Mx2N, 64x64/wave),
//    3 LDS slots x 48KB = 144KB. Iter t: vmcnt(6) [tile t landed, t+1 in
//    flight] -> barrier -> issue 6 gload_lds for tile t+2 -> ds_read+MFMA
//    tile t. Loads get ~2 iters to land; ONE barrier/iter; no mid-loop
//    vmcnt(0). Overwrite of slot (t+2)%3 is safe: its content was last
//    read in iter t-1, fenced by this iter's barrier.
//  - Kept verified pieces: XOR-swizzled 16B-chunk staging (0 conflicts
//    measured), i8 16x16x64 MFMA frag math, epilogue mapping (absmax 0.0).
//  - scaled-MFMA banned (R2/R4: 252+ regs, 10% occ). b64 LDS reads banned
//    (R5). logit = acc * (20/127^2); i8 loss error ~1e-3 via diag cancel.

#define AS1 __attribute__((address_space(1)))
#define AS3 __attribute__((address_space(3)))

constexpr int N = 4096;
constexpr int D = 1024;            // elements per row == bytes per i8 row
constexpr float QSCALE = 127.0f;
constexpr float LSCALE = 20.0f / (127.0f * 127.0f);  // acc -> logit
constexpr float CBIAS = 21.0f;     // >= max possible logit (20*1 + 1)

typedef int i32x4 __attribute__((ext_vector_type(4)));

// 3072 blocks x 256. One row per wave; lane holds 16 CONTIGUOUS floats ->
// 16 int8 bytes -> one uint4 store at byte 16*lane (wave writes 1KB contig).
// Blocks 0..15 also zero rowsum so gemm's atomics start clean.
__global__ __launch_bounds__(256) void normalize_kernel(
    const float* __restrict__ in0, const float* __restrict__ in1,
    const float* __restrict__ in2, unsigned char* __restrict__ Abuf,
    unsigned char* __restrict__ Bbuf, float* __restrict__ rowsum) {
    const int t = threadIdx.x, lane = t & 63, wave = t >> 6;
    if (blockIdx.x < 16) rowsum[blockIdx.x * 256 + t] = 0.f;
    const int row = blockIdx.x * 4 + wave;  // 0..12287
    const int mat = row >> 12, r = row & (N - 1);
    const float* src = (mat == 0) ? in0 : (mat == 1) ? in1 : in2;
    unsigned char* dst = (mat == 0) ? (Abuf + (size_t)r * D)
                       : (mat == 1) ? (Bbuf + (size_t)r * D)
                                    : (Bbuf + (size_t)(r + N) * D);
    const float4* s4 = (const float4*)(src + (size_t)r * D);
    float4 v[4];
    float p = 0.f;
#pragma unroll
    for (int j = 0; j < 4; ++j) {
        v[j] = s4[4 * lane + j];  // floats 16*lane .. 16*lane+15
        p += v[j].x * v[j].x + v[j].y * v[j].y + v[j].z * v[j].z + v[j].w * v[j].w;
    }
#pragma unroll
    for (int m = 1; m < 64; m <<= 1) p += __shfl_xor(p, m);
    const float s = QSCALE / fmaxf(sqrtf(p), 1e-8f);
    uint4 o;
    unsigned int w[4];
#pragma unroll
    for (int j = 0; j < 4; ++j) {
        int q0 = min(127, max(-127, __float2int_rn(v[j].x * s)));
        int q1 = min(127, max(-127, __float2int_rn(v[j].y * s)));
        int q2 = min(127, max(-127, __float2int_rn(v[j].z * s)));
        int q3 = min(127, max(-127, __float2int_rn(v[j].w * s)));
        w[j] = (q0 & 255) | ((q1 & 255) << 8) | ((q2 & 255) << 16)
             | ((unsigned)(q3 & 255) << 24);
    }
    o.x = w[0]; o.y = w[1]; o.z = w[2]; o.w = w[3];
    ((uint4*)dst)[lane] = o;
}

// 256x128 tile, BK=128 i8-bytes, 8 waves (4M x 2N), wave 64x64 via 4x4 of
// 16x16x64 i8 MFMA, 2 K-substeps (h) per K-tile, b128 frag reads.
// A:[N,D] i8, B:[2N,D] i8, row-major (frag = 16 contig bytes,
// row = lane&15, k = (lane>>4)*16 + j).
// C/D: col = lane&15, row = (lane>>4)*4 + reg (m89-verified, shape-determined).
// 3-slot LDS rotation, depth-2 prefetch, steady-state s_waitcnt vmcnt(6).
__global__ __launch_bounds__(512) void gemm_lse_kernel(
    const unsigned char* __restrict__ A, const unsigned char* __restrict__ B,
    float* __restrict__ rowsum, float* __restrict__ posdiag) {
    // slot s: A panel 256x128B (32KB) then B panel 128x128B (16KB)
    __shared__ __align__(16) char smem[3 * 49152];  // 144 KiB -> 1 block/CU

    const int tid = threadIdx.x;
    const int lane = tid & 63;
    const int wave = tid >> 6;        // 0..7
    const int wr = wave >> 1;         // 0..3: 64-row chunk of A panel
    const int wc = wave & 1;          // 0..1: 64-col chunk of B panel
    const int quad = lane >> 4, colid = lane & 15;
    const int rowBase = blockIdx.y * 256;
    const int colBase = blockIdx.x * 128;

    i32x4 acc[4][4];
#pragma unroll
    for (int i = 0; i < 4; ++i)
#pragma unroll
        for (int j = 0; j < 4; ++j) acc[i][j] = {0, 0, 0, 0};

    // Staging (R7/R8-verified geometry, 0 conflicts): 16B phys-chunks;
    // phys chunk c -> row c>>3, phys col c&7; logical col = (c&7)^(row&7).
    // A slot: 2048 chunks = 512 thr x 4; B slot: 1024 chunks = 512 thr x 2.
    const int srow = tid >> 3;                      // 0..63
    const int scol = (tid & 7) ^ ((tid >> 3) & 7);  // 16B units (row&7 == srow&7)
    const unsigned char* gA[4];
    const unsigned char* gB[2];
#pragma unroll
    for (int j = 0; j < 4; ++j)
        gA[j] = A + (size_t)(rowBase + srow + 64 * j) * D + scol * 16;
#pragma unroll
    for (int j = 0; j < 2; ++j)
        gB[j] = B + (size_t)(colBase + srow + 64 * j) * D + scol * 16;

    // Frag offsets: K-half h (64 K-elems), row R: logical chunk h*4+quad,
    // phys = logical ^ (R&7). One b128 IS the i8 MFMA operand (i32x4).
    int aoff[4][2], boff[4][2];
#pragma unroll
    for (int rt = 0; rt < 4; ++rt) {
        const int R = wr * 64 + rt * 16 + colid;
#pragma unroll
        for (int h = 0; h < 2; ++h)
            aoff[rt][h] = R * 128 + ((h * 4 + quad) ^ (R & 7)) * 16;
    }
#pragma unroll
    for (int ct = 0; ct < 4; ++ct) {
        const int C = wc * 64 + ct * 16 + colid;
#pragma unroll
        for (int h = 0; h < 2; ++h)
            boff[ct][h] = C * 128 + ((h * 4 + quad) ^ (C & 7)) * 16;
    }

    auto stage = [&](char* slot, int k0) {
        char* Ad = slot;
        char* Bd = slot + 32768;
#pragma unroll
        for (int j = 0; j < 4; ++j)
            __builtin_amdgcn_global_load_lds((const AS1 void*)(gA[j] + k0),
                (AS3 void*)(Ad + (tid + 512 * j) * 16), 16, 0, 0);
#pragma unroll
        for (int j = 0; j < 2; ++j)
            __builtin_amdgcn_global_load_lds((const AS1 void*)(gB[j] + k0),
                (AS3 void*)(Bd + (tid + 512 * j) * 16), 16, 0, 0);
    };

    // Prologue: prefetch K-tiles 0 and 1 (12 loads in flight).
    stage(smem + 0 * 49152, 0);
    stage(smem + 1 * 49152, 128);

    // Main loop: iter t computes K-tile t from slot t%3 and prefetches
    // K-tile t+2 into slot (t+2)%3. vmcnt(6): my 6 tile-t loads retired,
    // tile-(t+1)'s 6 stay in flight (never drain to 0 mid-loop). The
    // barrier then makes ALL waves' tile-t loads visible, and fences all
    // reads of slot (t+2)%3's old content (done in iter t-1, before each
    // wave's own MFMAs -> before this barrier).
#pragma unroll
    for (int t = 0; t < 8; ++t) {
        if (t < 7)
            asm volatile("s_waitcnt vmcnt(6)" ::: "memory");
        else
            asm volatile("s_waitcnt vmcnt(0)" ::: "memory");
        __builtin_amdgcn_s_barrier();
        if (t < 6) stage(smem + ((t + 2) % 3) * 49152, (t + 2) * 128);

        const char* Ab = smem + (t % 3) * 49152;
        const char* Bb = Ab + 32768;
#pragma unroll
        for (int h = 0; h < 2; ++h) {
            i32x4 a[4], b[4];
#pragma unroll
            for (int rt = 0; rt < 4; ++rt)
                a[rt] = *(const i32x4*)(Ab + aoff[rt][h]);
#pragma unroll
            for (int ct = 0; ct < 4; ++ct)
                b[ct] = *(const i32x4*)(Bb + boff[ct][h]);
            __builtin_amdgcn_s_setprio(1);
#pragma unroll
            for (int rt = 0; rt < 4; ++rt)
#pragma unroll
                for (int ct = 0; ct < 4; ++ct)
                    acc[rt][ct] = __builtin_amdgcn_mfma_i32_16x16x64_i8(
                        a[rt], b[ct], acc[rt][ct], 0, 0, 0);
            __builtin_amdgcn_s_setprio(0);
        }
    }

    // Epilogue: C map col = lane&15, row = quad*4 + reg.
#pragma unroll
    for (int rt = 0; rt < 4; ++rt) {
        float rsum[4] = {0.f, 0.f, 0.f, 0.f};
#pragma unroll
        for (int ct = 0; ct < 4; ++ct) {
#pragma unroll
            for (int reg = 0; reg < 4; ++reg) {
                const int grow = rowBase + wr * 64 + rt * 16 + quad * 4 + reg;
                const int gcol = colBase + wc * 64 + ct * 16 + colid;
                float logit = (float)acc[rt][ct][reg] * LSCALE;
                if (gcol == grow + N) logit += 1.0f;      // hard-negative weight
                if (gcol == grow) posdiag[grow] = logit;  // unique writer
                rsum[reg] += __expf(logit - CBIAS);
            }
        }
#pragma unroll
        for (int reg = 0; reg < 4; ++reg) {
            float v = rsum[reg];
            v += __shfl_xor(v, 1);
            v += __shfl_xor(v, 2);
            v += __shfl_xor(v, 4);
            v += __shfl_xor(v, 8);
            if (colid == 0) {
                const int grow = rowBase + wr * 64 + rt * 16 + quad * 4 + reg;
                atomicAdd(&rowsum[grow], v);
            }
        }
    }
}

__global__ __launch_bounds__(256) void finalize_kernel(
    const float* __restrict__ rowsum, const float* __restrict__ posdiag,
    float* __restrict__ out) {
    const int t = threadIdx.x;
    float s = 0.f;
    for (int i = t; i < N; i += 256)
        s += CBIAS + logf(rowsum[i]) - posdiag[i];
    for (int m = 32; m; m >>= 1) s += __shfl_down(s, m);
    __shared__ float red[4];
    const int lane = t & 63, wave = t >> 6;
    if (lane == 0) red[wave] = s;
    __syncthreads();
    if (t == 0) out[0] = (red[0] + red[1] + red[2] + red[3]) / (float)N;
}

extern "C" void kernel_launch(void* const* d_in, const int* in_sizes, int n_in,
                              void* d_out, int out_size, void* d_ws, size_t ws_size,
                              hipStream_t stream) {
    const float* in0 = (const float*)d_in[0];  // input   [N, D] fp32
    const float* in1 = (const float*)d_in[1];  // target  [N, D] fp32
    const float* in2 = (const float*)d_in[2];  // hardneg [N, D] fp32

    // Workspace: Abuf N*D i8 (4 MiB) | Bbuf 2N*D i8 (8 MiB) | rowsum | posdiag
    unsigned char* Abuf = (unsigned char*)d_ws;
    unsigned char* Bbuf = Abuf + (size_t)N * D;
    float* rowsum = (float*)(Bbuf + (size_t)2 * N * D);
    float* posdiag = rowsum + N;

    normalize_kernel<<<3 * N / 4, 256, 0, stream>>>(in0, in1, in2, Abuf, Bbuf,
                                                    rowsum);
    gemm_lse_kernel<<<dim3(2 * N / 128, N / 256), 512, 0, stream>>>(
        Abuf, Bbuf, rowsum, posdiag);
    finalize_kernel<<<1, 256, 0, stream>>>(rowsum, posdiag, (float*)d_out);
}

// Round 3
// 158.154 us; speedup vs baseline: 1.0627x; 1.0283x over previous
//
#include <hip/hip_runtime.h>
#include <hip/hip_bf16.h>

// ContrastiveLoss: loss = mean_i [ logsumexp_j(logits[i,:]) - pos_sim[i,i] ]
// logits = [20*xn@tn^T | 20*xn@hn^T + I], rows normalized.
// Round 11: full 8-phase-style schedule (catalog T2+T3+T4+T5 combo).
//  - R8 (serial drain) / R9 (dbuf) / R10 (3-slot counted-vmcnt rotation) all
//    land 73-84us @ 15-18% MfmaUtil: counted-vmcnt on a coarse 2-barrier
//    K-loop is NULL (matches m230 regime gate). The gate is the fine phase
//    split: per phase {8 ds_read_b128 || 2 gload_lds -> barrier ->
//    lgkmcnt(0) -> 16 MFMA (setprio) -> barrier}.
//  - BM=BN=256, K-slice=64B (one i8 MFMA K-step), 16 slices, 4 LDS slots x
//    32KB = 128KB (1 blk/CU, 8 waves 2Mx4N, wave = 128x64 out).
//  - 2 phases/slice (row-half each). Stage stream 3 slices ahead: A-half in
//    even phase, B-half in odd phase; vmcnt(8) once per slice after odd
//    MFMA cluster (tiles k+2,k+3 in flight; k+1 landed). Slot reuse
//    distance 4 slices, overwrite 1 barrier-phase after last read.
//  - 64B-row XOR swizzle: phys_chunk = quad ^ (colid&3) ^ (colid>>2);
//    <=2 lanes/bank per 16-lane phase (2-way free, m136). Staging writes
//    linear LDS, inverse permutation folded into per-lane global col.
//  - scaled-MFMA banned (R2/R4: 252+ regs). b64 LDS reads banned (R5).
//  - logit = acc * (20/127^2); i8 loss error ~1e-3 via diag cancellation.

#define AS1 __attribute__((address_space(1)))
#define AS3 __attribute__((address_space(3)))

constexpr int N = 4096;
constexpr int D = 1024;            // elements per row == bytes per i8 row
constexpr float QSCALE = 127.0f;
constexpr float LSCALE = 20.0f / (127.0f * 127.0f);  // acc -> logit
constexpr float CBIAS = 21.0f;     // >= max possible logit (20*1 + 1)

typedef int i32x4 __attribute__((ext_vector_type(4)));

// 3072 blocks x 256. One row per wave; lane holds 16 CONTIGUOUS floats ->
// 16 int8 bytes -> one uint4 store at byte 16*lane (wave writes 1KB contig).
// Blocks 0..15 also zero rowsum so gemm's atomics start clean.
__global__ __launch_bounds__(256) void normalize_kernel(
    const float* __restrict__ in0, const float* __restrict__ in1,
    const float* __restrict__ in2, unsigned char* __restrict__ Abuf,
    unsigned char* __restrict__ Bbuf, float* __restrict__ rowsum) {
    const int t = threadIdx.x, lane = t & 63, wave = t >> 6;
    if (blockIdx.x < 16) rowsum[blockIdx.x * 256 + t] = 0.f;
    const int row = blockIdx.x * 4 + wave;  // 0..12287
    const int mat = row >> 12, r = row & (N - 1);
    const float* src = (mat == 0) ? in0 : (mat == 1) ? in1 : in2;
    unsigned char* dst = (mat == 0) ? (Abuf + (size_t)r * D)
                       : (mat == 1) ? (Bbuf + (size_t)r * D)
                                    : (Bbuf + (size_t)(r + N) * D);
    const float4* s4 = (const float4*)(src + (size_t)r * D);
    float4 v[4];
    float p = 0.f;
#pragma unroll
    for (int j = 0; j < 4; ++j) {
        v[j] = s4[4 * lane + j];  // floats 16*lane .. 16*lane+15
        p += v[j].x * v[j].x + v[j].y * v[j].y + v[j].z * v[j].z + v[j].w * v[j].w;
    }
#pragma unroll
    for (int m = 1; m < 64; m <<= 1) p += __shfl_xor(p, m);
    const float s = QSCALE / fmaxf(sqrtf(p), 1e-8f);
    uint4 o;
    unsigned int w[4];
#pragma unroll
    for (int j = 0; j < 4; ++j) {
        int q0 = min(127, max(-127, __float2int_rn(v[j].x * s)));
        int q1 = min(127, max(-127, __float2int_rn(v[j].y * s)));
        int q2 = min(127, max(-127, __float2int_rn(v[j].z * s)));
        int q3 = min(127, max(-127, __float2int_rn(v[j].w * s)));
        w[j] = (q0 & 255) | ((q1 & 255) << 8) | ((q2 & 255) << 16)
             | ((unsigned)(q3 & 255) << 24);
    }
    o.x = w[0]; o.y = w[1]; o.z = w[2]; o.w = w[3];
    ((uint4*)dst)[lane] = o;
}

// 256x256 tile, K-slice 64B, 8 waves (2M x 4N), wave 128x64 via 8x4 of
// 16x16x64 i8 MFMA per slice (16 MFMA per phase, 2 phases/slice).
// A:[N,D] i8, B:[2N,D] i8, row-major. A/B frag: row = lane&15, k-bytes
// quad*16..+15 of the 64B slice row. C/D: col = lane&15,
// row = (lane>>4)*4 + reg (m89-verified, shape-determined).
__global__ __launch_bounds__(512) void gemm_lse_kernel(
    const unsigned char* __restrict__ A, const unsigned char* __restrict__ B,
    float* __restrict__ rowsum, float* __restrict__ posdiag) {
    // slot s (s = slice & 3): A panel 256x64B (16KB) then B panel (16KB).
    __shared__ __align__(16) char smem[4 * 32768];  // 128 KiB -> 1 block/CU

    const int tid = threadIdx.x;
    const int lane = tid & 63;
    const int wave = tid >> 6;       // 0..7
    const int wm = wave >> 2;        // 0..1 : 128-row half of A tile
    const int wn = wave & 3;         // 0..3 : 64-col chunk of B tile
    const int quad = lane >> 4, colid = lane & 15;
    const int rowBase = blockIdx.y * 256;
    const int colBase = blockIdx.x * 256;

    i32x4 acc[8][4];
#pragma unroll
    for (int i = 0; i < 8; ++i)
#pragma unroll
        for (int j = 0; j < 4; ++j) acc[i][j] = {0, 0, 0, 0};

    // Staging: panel = 1024 16B phys-chunks; thread t writes chunks t, t+512
    // (rows t>>2 and t>>2+128). phys chunk c: row = c>>2, phys col = c&3;
    // logical col = (c&3) ^ (row&3) ^ ((row>>2)&3)  [same for both rows].
    const int srow = tid >> 2;  // 0..127
    const int lcol = (tid & 3) ^ (srow & 3) ^ ((srow >> 2) & 3);
    const unsigned char* gA0 = A + (size_t)(rowBase + srow) * D + lcol * 16;
    const unsigned char* gA1 = A + (size_t)(rowBase + srow + 128) * D + lcol * 16;
    const unsigned char* gB0 = B + (size_t)(colBase + srow) * D + lcol * 16;
    const unsigned char* gB1 = B + (size_t)(colBase + srow + 128) * D + lcol * 16;

    auto stageA = [&](int kt) {
        char* slot = smem + (kt & 3) * 32768;
        __builtin_amdgcn_global_load_lds((const AS1 void*)(gA0 + kt * 64),
            (AS3 void*)(slot + tid * 16), 16, 0, 0);
        __builtin_amdgcn_global_load_lds((const AS1 void*)(gA1 + kt * 64),
            (AS3 void*)(slot + (tid + 512) * 16), 16, 0, 0);
    };
    auto stageB = [&](int kt) {
        char* slot = smem + (kt & 3) * 32768 + 16384;
        __builtin_amdgcn_global_load_lds((const AS1 void*)(gB0 + kt * 64),
            (AS3 void*)(slot + tid * 16), 16, 0, 0);
        __builtin_amdgcn_global_load_lds((const AS1 void*)(gB1 + kt * 64),
            (AS3 void*)(slot + (tid + 512) * 16), 16, 0, 0);
    };

    // Frag read offsets within a slot. Row R's logical chunk q sits at phys
    // chunk q ^ (R&3) ^ ((R>>2)&3); with R = base16 + colid (base16 mult of
    // 16) that is q ^ (colid&3) ^ (colid>>2) -- row-tile independent.
    const int chunkSw = quad ^ (colid & 3) ^ (colid >> 2);
    int aoff[8], boff[4];
#pragma unroll
    for (int rt = 0; rt < 8; ++rt)
        aoff[rt] = (wm * 128 + rt * 16 + colid) * 64 + chunkSw * 16;
#pragma unroll
    for (int ct = 0; ct < 4; ++ct)
        boff[ct] = 16384 + (wn * 64 + ct * 16 + colid) * 64 + chunkSw * 16;

    // Prologue: stage slices 0,1,2 (12 loads); require slice 0 landed
    // (allow 8 outstanding = slices 1,2).
    stageA(0); stageB(0);
    stageA(1); stageB(1);
    stageA(2); stageB(2);
    asm volatile("s_waitcnt vmcnt(8)" ::: "memory");
    __builtin_amdgcn_s_barrier();

    // Main loop: slice k, 2 phases. Even phase: read a[0..3] (rows wm*128 +
    // 0..63) + b[0..3], stage A(k+3); MFMA quadrants rt 0-3. Odd phase:
    // read a[4..7], stage B(k+3); MFMA rt 4-7; counted vmcnt before the
    // trailing barrier guarantees slice k+1 is resident for the next
    // phase's ds_reads. Slot (k+3)&3's old content (slice k-1) was last
    // read one phase ago, fenced by the intervening barrier.
#pragma unroll
    for (int k = 0; k < 16; ++k) {
        const char* sl = smem + (k & 3) * 32768;
        i32x4 a[4], b[4];
        // ---- even phase ----
#pragma unroll
        for (int rt = 0; rt < 4; ++rt)
            a[rt] = *(const i32x4*)(sl + aoff[rt]);
#pragma unroll
        for (int ct = 0; ct < 4; ++ct)
            b[ct] = *(const i32x4*)(sl + boff[ct]);
        if (k < 13) stageA(k + 3);
        __builtin_amdgcn_s_barrier();
        asm volatile("s_waitcnt lgkmcnt(0)" ::: "memory");
        __builtin_amdgcn_s_setprio(1);
#pragma unroll
        for (int rt = 0; rt < 4; ++rt)
#pragma unroll
            for (int ct = 0; ct < 4; ++ct)
                acc[rt][ct] = __builtin_amdgcn_mfma_i32_16x16x64_i8(
                    a[rt], b[ct], acc[rt][ct], 0, 0, 0);
        __builtin_amdgcn_s_setprio(0);
        __builtin_amdgcn_s_barrier();
        // ---- odd phase ----
        i32x4 a2[4];
#pragma unroll
        for (int rt = 0; rt < 4; ++rt)
            a2[rt] = *(const i32x4*)(sl + aoff[4 + rt]);
        if (k < 13) stageB(k + 3);
        __builtin_amdgcn_s_barrier();
        asm volatile("s_waitcnt lgkmcnt(0)" ::: "memory");
        __builtin_amdgcn_s_setprio(1);
#pragma unroll
        for (int rt = 0; rt < 4; ++rt)
#pragma unroll
            for (int ct = 0; ct < 4; ++ct)
                acc[4 + rt][ct] = __builtin_amdgcn_mfma_i32_16x16x64_i8(
                    a2[rt], b[ct], acc[4 + rt][ct], 0, 0, 0);
        __builtin_amdgcn_s_setprio(0);
        // Counted checkpoint (once per slice, after MFMA, before barrier):
        // k<=12: 8 outstanding = slices k+2,k+3; slice k+1 landed.
        // k==13: only A/B(15) outstanding -> 4; k==14: none -> 0.
        if (k <= 12)
            asm volatile("s_waitcnt vmcnt(8)" ::: "memory");
        else if (k == 13)
            asm volatile("s_waitcnt vmcnt(4)" ::: "memory");
        else if (k == 14)
            asm volatile("s_waitcnt vmcnt(0)" ::: "memory");
        __builtin_amdgcn_s_barrier();
    }

    // Epilogue: C map col = lane&15, row = quad*4 + reg.
#pragma unroll
    for (int rt = 0; rt < 8; ++rt) {
        float rsum[4] = {0.f, 0.f, 0.f, 0.f};
#pragma unroll
        for (int ct = 0; ct < 4; ++ct) {
#pragma unroll
            for (int reg = 0; reg < 4; ++reg) {
                const int grow = rowBase + wm * 128 + rt * 16 + quad * 4 + reg;
                const int gcol = colBase + wn * 64 + ct * 16 + colid;
                float logit = (float)acc[rt][ct][reg] * LSCALE;
                if (gcol == grow + N) logit += 1.0f;      // hard-negative weight
                if (gcol == grow) posdiag[grow] = logit;  // unique writer
                rsum[reg] += __expf(logit - CBIAS);
            }
        }
#pragma unroll
        for (int reg = 0; reg < 4; ++reg) {
            float v = rsum[reg];
            v += __shfl_xor(v, 1);
            v += __shfl_xor(v, 2);
            v += __shfl_xor(v, 4);
            v += __shfl_xor(v, 8);
            if (colid == 0) {
                const int grow = rowBase + wm * 128 + rt * 16 + quad * 4 + reg;
                atomicAdd(&rowsum[grow], v);
            }
        }
    }
}

__global__ __launch_bounds__(256) void finalize_kernel(
    const float* __restrict__ rowsum, const float* __restrict__ posdiag,
    float* __restrict__ out) {
    const int t = threadIdx.x;
    float s = 0.f;
    for (int i = t; i < N; i += 256)
        s += CBIAS + logf(rowsum[i]) - posdiag[i];
    for (int m = 32; m; m >>= 1) s += __shfl_down(s, m);
    __shared__ float red[4];
    const int lane = t & 63, wave = t >> 6;
    if (lane == 0) red[wave] = s;
    __syncthreads();
    if (t == 0) out[0] = (red[0] + red[1] + red[2] + red[3]) / (float)N;
}

extern "C" void kernel_launch(void* const* d_in, const int* in_sizes, int n_in,
                              void* d_out, int out_size, void* d_ws, size_t ws_size,
                              hipStream_t stream) {
    const float* in0 = (const float*)d_in[0];  // input   [N, D] fp32
    const float* in1 = (const float*)d_in[1];  // target  [N, D] fp32
    const float* in2 = (const float*)d_in[2];  // hardneg [N, D] fp32

    // Workspace: Abuf N*D i8 (4 MiB) | Bbuf 2N*D i8 (8 MiB) | rowsum | posdiag
    unsigned char* Abuf = (unsigned char*)d_ws;
    unsigned char* Bbuf = Abuf + (size_t)N * D;
    float* rowsum = (float*)(Bbuf + (size_t)2 * N * D);
    float* posdiag = rowsum + N;

    normalize_kernel<<<3 * N / 4, 256, 0, stream>>>(in0, in1, in2, Abuf, Bbuf,
                                                    rowsum);
    gemm_lse_kernel<<<dim3(2 * N / 256, N / 256), 512, 0, stream>>>(
        Abuf, Bbuf, rowsum, posdiag);
    finalize_kernel<<<1, 256, 0, stream>>>(rowsum, posdiag, (float*)d_out);
}